// Round 1
// baseline (28.284 us; speedup 1.0000x reference)
//
#include <hip/hip_runtime.h>

// CapsuleMaxPooling: inp [B=32, C=32, H=64, W=64, D=8] f32, k=2.
// Output [32, 32, 32, 32, 8]: per 2x2 spatial window pick capsule (D-vector)
// with largest squared L2 norm (first-max tie-break).
//
// Geometry baked in: BC = B*C = 1024, H=W=64, Hk=Wk=32, D=8.
// One thread per output window. Each capsule = 8 floats = 2 x float4.

__global__ __launch_bounds__(256) void capsule_maxpool_kernel(
    const float* __restrict__ inp, float* __restrict__ out, int n_windows) {
    int idx = blockIdx.x * blockDim.x + threadIdx.x;
    if (idx >= n_windows) return;

    // idx = ((bc*32 + hk)*32 + wk)
    int wk = idx & 31;
    int hk = (idx >> 5) & 31;
    int bc = idx >> 10;

    // input element offset of (bc, h=2*hk, w=2*wk, d=0)
    size_t base = (((size_t)bc * 64 + 2 * hk) * 64 + 2 * wk) * 8;
    const float4* row0 = reinterpret_cast<const float4*>(inp + base);
    const float4* row1 = reinterpret_cast<const float4*>(inp + base + 64 * 8); // h+1

    // window order after reshape/transpose: (kh, kw) -> kh*2 + kw
    // cap0 = (0,0), cap1 = (0,1), cap2 = (1,0), cap3 = (1,1)
    float4 a0 = row0[0], a1 = row0[1];   // cap0
    float4 b0 = row0[2], b1 = row0[3];   // cap1
    float4 c0 = row1[0], c1 = row1[1];   // cap2
    float4 d0 = row1[2], d1 = row1[3];   // cap3

    float n0 = a0.x*a0.x + a0.y*a0.y + a0.z*a0.z + a0.w*a0.w
             + a1.x*a1.x + a1.y*a1.y + a1.z*a1.z + a1.w*a1.w;
    float n1 = b0.x*b0.x + b0.y*b0.y + b0.z*b0.z + b0.w*b0.w
             + b1.x*b1.x + b1.y*b1.y + b1.z*b1.z + b1.w*b1.w;
    float n2 = c0.x*c0.x + c0.y*c0.y + c0.z*c0.z + c0.w*c0.w
             + c1.x*c1.x + c1.y*c1.y + c1.z*c1.z + c1.w*c1.w;
    float n3 = d0.x*d0.x + d0.y*d0.y + d0.z*d0.z + d0.w*d0.w
             + d1.x*d1.x + d1.y*d1.y + d1.z*d1.z + d1.w*d1.w;

    // first-max: strictly-greater chain keeps earliest index on ties.
    float best = n0;
    float4 s0 = a0, s1 = a1;
    if (n1 > best) { best = n1; s0 = b0; s1 = b1; }
    if (n2 > best) { best = n2; s0 = c0; s1 = c1; }
    if (n3 > best) { best = n3; s0 = d0; s1 = d1; }

    float4* o = reinterpret_cast<float4*>(out + (size_t)idx * 8);
    o[0] = s0;
    o[1] = s1;
}

extern "C" void kernel_launch(void* const* d_in, const int* in_sizes, int n_in,
                              void* d_out, int out_size, void* d_ws, size_t ws_size,
                              hipStream_t stream) {
    const float* inp = (const float*)d_in[0];
    float* out = (float*)d_out;
    // n_windows = out_size / D = 8388608 / 8 = 1048576
    int n_windows = out_size / 8;
    int block = 256;
    int grid = (n_windows + block - 1) / block;
    capsule_maxpool_kernel<<<grid, block, 0, stream>>>(inp, out, n_windows);
}